// Round 8
// baseline (342.569 us; speedup 1.0000x reference)
//
#include <hip/hip_runtime.h>
#include <math.h>

// Problem constants
#define Bn   32
#define Cn   684
#define Hn   16
#define Wn   64
#define HWn  1024
#define HIDn 256
#define An   512
#define KKn  121           // 11*11
#define CREAL 805          // 684 + 121
#define CPAD 832           // 26 chunks of 32 (row stride of Xt and VTbf)
#define NSTEP 26

// Output layout (flat fp32): context [32,684] | alpha [32,1024] | alpha_sum_new [32,1024]
#define OUT_ALPHA 21888
#define OUT_ASUM  (21888 + 32768)

typedef short short8 __attribute__((ext_vector_type(8)));     // 8 bf16 = 4 VGPRs
typedef float floatx4 __attribute__((ext_vector_type(4)));    // MFMA acc

__device__ __forceinline__ float bf2f(unsigned short u) {
    union { unsigned int i; float f; } v; v.i = ((unsigned int)u) << 16; return v.f;
}
__device__ __forceinline__ unsigned short f2bf(float f) {
    union { float f; unsigned int i; } v; v.f = f;
    unsigned int i = v.i;
    return (unsigned short)((i + 0x7fffu + ((i >> 16) & 1u)) >> 16);
}
__device__ __forceinline__ unsigned int pack2bf(float v0, float v1) {
    unsigned int u0 = __float_as_uint(v0), u1 = __float_as_uint(v1);
    u0 = (u0 + 0x7fffu + ((u0 >> 16) & 1u)) >> 16;
    u1 = (u1 + 0x7fffu + ((u1 >> 16) & 1u)) & 0xffff0000u;
    return u0 | u1;
}

// ---------------------------------------------------------------------------
// K_prep: three block families in one launch.
//   blocks 0..511     : tiled transpose  Xt[b][hw][c'] bf16  (im2col baked in)
//   blocks 512..1023  : build VTbf row a  (k-contiguous)
//   blocks 1024..1055 : query[b,a] = bh[a]+bec[a]+hidden[b]·Wh[a]
__global__ __launch_bounds__(256) void k_prep(
    const float* __restrict__ X,
    const float* __restrict__ asum,
    const float* __restrict__ hidden,
    const float* __restrict__ Wh,
    const float* __restrict__ bh,
    const float* __restrict__ bec,
    const float* __restrict__ Wec,
    const float* __restrict__ Wac,
    const float* __restrict__ Waw,
    float* __restrict__ query,
    unsigned short* __restrict__ VTbf,
    unsigned short* __restrict__ Xt)
{
    __shared__ float smem[9200];   // aliased per branch (36.8 KB)
    const int blk = blockIdx.x, t = threadIdx.x;
    const int lane = t & 63, wid = t >> 6;

    if (blk < 512) {
        // ---- transpose branch: block = (b, h-row); 64 hw x 832 c'
        float* tile  = smem;               // [128][65] fp32
        float* plane = smem + 128 * 65;    // [11][74]
        const int b = blk >> 4, h = blk & 15;
        for (int i = t; i < 11 * 74; i += 256) {
            int di = i / 74, cc = i - di * 74;
            int h2 = h + di - 5, w2 = cc - 5;
            float v = 0.f;
            if (h2 >= 0 && h2 < Hn && w2 >= 0 && w2 < Wn)
                v = asum[b * HWn + h2 * Wn + w2];
            plane[i] = v;
        }
        // 6 c-tile passes over X (c 0..683)
        for (int p = 0; p < 6; ++p) {
            const int c0 = p * 128;
            const int nc = (c0 + 128 <= Cn) ? 128 : (Cn - c0);   // 128 or 44
            __syncthreads();
            #pragma unroll 8
            for (int i = 0; i < 32; ++i) {
                int c = i * 4 + wid;
                if (c < nc)
                    tile[c * 65 + lane] =
                        X[((size_t)(b * Cn + c0 + c)) * HWn + h * 64 + lane];
            }
            __syncthreads();
            const int cc = 2 * lane;
            #pragma unroll
            for (int j = 0; j < 16; ++j) {
                int hwr = j * 4 + wid;
                if (cc + 1 < nc) {
                    unsigned int u = pack2bf(tile[cc * 65 + hwr],
                                             tile[(cc + 1) * 65 + hwr]);
                    *(unsigned int*)(Xt + (size_t)(b * HWn + h * 64 + hwr) * CPAD
                                     + c0 + cc) = u;
                }
            }
        }
        // im2col + zero tail: c' 684..831 straight from plane (coalesced rows)
        if (lane < 74) {
            const int c0 = Cn + 2 * lane;
            #pragma unroll
            for (int j = 0; j < 16; ++j) {
                int hwr = j * 4 + wid;
                float v0 = 0.f, v1 = 0.f;
                if (c0 < CREAL) {
                    int ij = c0 - Cn; int di = ij / 11, dj = ij - di * 11;
                    v0 = plane[di * 74 + hwr + dj];
                }
                if (c0 + 1 < CREAL) {
                    int ij = c0 + 1 - Cn; int di = ij / 11, dj = ij - di * 11;
                    v1 = plane[di * 74 + hwr + dj];
                }
                *(unsigned int*)(Xt + (size_t)(b * HWn + h * 64 + hwr) * CPAD
                                 + c0) = pack2bf(v0, v1);
            }
        }
    } else if (blk < 1024) {
        // ---- VTbf branch
        float* sbuf  = smem;          // [512]
        float* wac_s = smem + 512;    // [64*121]
        const int a = blk - 512;
        sbuf[t]       = Waw[(size_t)a * 512 + t];
        sbuf[t + 256] = Waw[(size_t)a * 512 + t + 256];
        for (int cp = t; cp < Cn; cp += 256)
            VTbf[(size_t)a * CPAD + cp] = f2bf(Wec[(size_t)a * Cn + cp]);
        float s = 0.f;
        for (int kb = 0; kb < 8; ++kb) {
            __syncthreads();
            for (int i = t; i < 64 * KKn; i += 256)
                wac_s[i] = Wac[kb * 64 * KKn + i];     // coalesced
            __syncthreads();
            if (t < KKn) {
                #pragma unroll 8
                for (int kk = 0; kk < 64; ++kk)
                    s = fmaf(sbuf[kb * 64 + kk], wac_s[kk * KKn + t], s);
            }
        }
        if (t < KKn)
            VTbf[(size_t)a * CPAD + Cn + t] = f2bf(s);
        for (int cp = CREAL + t; cp < CPAD; cp += 256)
            VTbf[(size_t)a * CPAD + cp] = 0;
    } else {
        // ---- query branch
        float* sbuf = smem;
        const int b = blk - 1024;
        sbuf[t] = (t < HIDn) ? hidden[b * HIDn + t] : 0.f;
        __syncthreads();
        for (int a = t; a < An; a += 256) {
            const float4* wp = (const float4*)(Wh + (size_t)a * HIDn);
            float s = bh[a] + bec[a];
            #pragma unroll 8
            for (int i = 0; i < HIDn / 4; ++i) {
                float4 w = wp[i];
                s = fmaf(sbuf[4 * i],     w.x, s);
                s = fmaf(sbuf[4 * i + 1], w.y, s);
                s = fmaf(sbuf[4 * i + 2], w.z, s);
                s = fmaf(sbuf[4 * i + 3], w.w, s);
            }
            query[b * An + a] = s;
        }
    }
}

// ---------------------------------------------------------------------------
// K_energy v7: barrier-free, LDS-free main loop. Block = (b,hh): M=64, N=512,
// K=832. Wave owns 128-a panel: 4x8 frags, 32 MFMA / K-chunk. A and B frags
// load DIRECTLY from bf16 k-contiguous global (Xt L1/L2, VTbf L2-resident).
__global__ __launch_bounds__(256, 2) void k_energy(
    const unsigned short* __restrict__ Xt,
    const float* __restrict__ Wv,
    const float* __restrict__ query,
    const unsigned short* __restrict__ VTbf,
    float* __restrict__ energy)
{
    __shared__ float red[64 * 65];
    __shared__ float qs[An];
    __shared__ float wvs[An];

    const int t = threadIdx.x;
    const int hh = blockIdx.x, b = blockIdx.y;
    const int w = t >> 6, lane = t & 63;
    const int q = lane >> 4, r = lane & 15;

    qs[t]        = query[b * An + t];
    qs[t + 256]  = query[b * An + t + 256];
    wvs[t]       = Wv[t];
    wvs[t + 256] = Wv[t + 256];

    const unsigned short* Arow = Xt + (size_t)(b * HWn + hh * Wn) * CPAD + r * CPAD + q * 8;
    const unsigned short* Brow = VTbf + (size_t)(w * 128) * CPAD + r * CPAD + q * 8;

    floatx4 acc[4][8];
    #pragma unroll
    for (int mf = 0; mf < 4; ++mf)
        #pragma unroll
        for (int nf = 0; nf < 8; ++nf)
            acc[mf][nf] = (floatx4){0.f, 0.f, 0.f, 0.f};

    short8 af[4], bfA[8], bfB[8];
    #pragma unroll
    for (int nf = 0; nf < 8; ++nf)
        bfA[nf] = *(const short8*)(Brow + (size_t)(nf * 16) * CPAD);

    for (int ch = 0; ch < NSTEP; ch += 2) {
        const int c0 = ch * 32;
        // chunk ch: A loads, B prefetch for ch+1, MFMA
        #pragma unroll
        for (int mf = 0; mf < 4; ++mf)
            af[mf] = *(const short8*)(Arow + (size_t)(mf * 16) * CPAD + c0);
        #pragma unroll
        for (int nf = 0; nf < 8; ++nf)
            bfB[nf] = *(const short8*)(Brow + (size_t)(nf * 16) * CPAD + c0 + 32);
        #pragma unroll
        for (int mf = 0; mf < 4; ++mf)
            #pragma unroll
            for (int nf = 0; nf < 8; ++nf)
                acc[mf][nf] = __builtin_amdgcn_mfma_f32_16x16x32_bf16(
                    af[mf], bfA[nf], acc[mf][nf], 0, 0, 0);
        // chunk ch+1: A loads, B prefetch for ch+2, MFMA
        #pragma unroll
        for (int mf = 0; mf < 4; ++mf)
            af[mf] = *(const short8*)(Arow + (size_t)(mf * 16) * CPAD + c0 + 32);
        if (ch + 2 < NSTEP) {
            #pragma unroll
            for (int nf = 0; nf < 8; ++nf)
                bfA[nf] = *(const short8*)(Brow + (size_t)(nf * 16) * CPAD + c0 + 64);
        }
        #pragma unroll
        for (int mf = 0; mf < 4; ++mf)
            #pragma unroll
            for (int nf = 0; nf < 8; ++nf)
                acc[mf][nf] = __builtin_amdgcn_mfma_f32_16x16x32_bf16(
                    af[mf], bfB[nf], acc[mf][nf], 0, 0, 0);
    }

    // ---- epilogue: e[m] = sum_n Wv[n]*tanh(acc + query[n])
    float ep[16];
    #pragma unroll
    for (int i = 0; i < 16; ++i) ep[i] = 0.f;
    #pragma unroll
    for (int nf = 0; nf < 8; ++nf) {
        int n = w * 128 + nf * 16 + r;
        float qv = qs[n], wv = wvs[n];
        #pragma unroll
        for (int mf = 0; mf < 4; ++mf)
            #pragma unroll
            for (int rg = 0; rg < 4; ++rg) {
                float x = acc[mf][nf][rg] + qv;
                float e2 = __expf(2.f * x);
                float th = 1.f - 2.f * __builtin_amdgcn_rcpf(e2 + 1.f);
                ep[mf * 4 + rg] += wv * th;
            }
    }
    __syncthreads();
    #pragma unroll
    for (int mf = 0; mf < 4; ++mf)
        #pragma unroll
        for (int rg = 0; rg < 4; ++rg)
            red[(mf * 16 + q * 4 + rg) * 65 + w * 16 + r] = ep[mf * 4 + rg];
    __syncthreads();
    if (t < 64) {
        float s = 0.f;
        #pragma unroll 16
        for (int i = 0; i < 64; ++i) s += red[t * 65 + i];
        energy[b * HWn + hh * Wn + t] = s;
    }
}

// ---------------------------------------------------------------------------
// K_ctx: fused softmax + context from Xt. Grid (16 hw-chunks, 32 b).
__global__ __launch_bounds__(256) void k_ctx(
    const unsigned short* __restrict__ Xt,
    const float* __restrict__ energy,
    const float* __restrict__ mask,
    const float* __restrict__ asum,
    float* __restrict__ out)
{
    __shared__ float al[1024];
    __shared__ float rsm[8];
    const int hhc = blockIdx.x, b = blockIdx.y;
    const int t = threadIdx.x, lane = t & 63, wid = t >> 6;

    float e[4], ex[4];
    #pragma unroll
    for (int i = 0; i < 4; ++i) e[i] = energy[b * HWn + i * 256 + t];
    float m = fmaxf(fmaxf(e[0], e[1]), fmaxf(e[2], e[3]));
    for (int off = 32; off >= 1; off >>= 1) m = fmaxf(m, __shfl_down(m, off, 64));
    if (lane == 0) rsm[wid] = m;
    __syncthreads();
    if (t == 0) rsm[4] = fmaxf(fmaxf(rsm[0], rsm[1]), fmaxf(rsm[2], rsm[3]));
    __syncthreads();
    const float M = rsm[4];
    float s = 0.f;
    #pragma unroll
    for (int i = 0; i < 4; ++i) {
        ex[i] = expf(e[i] - M) * mask[b * HWn + i * 256 + t];
        s += ex[i];
    }
    for (int off = 32; off >= 1; off >>= 1) s += __shfl_down(s, off, 64);
    __syncthreads();
    if (lane == 0) rsm[wid] = s;
    __syncthreads();
    if (t == 0) rsm[5] = rsm[0] + rsm[1] + rsm[2] + rsm[3] + 1e-10f;
    __syncthreads();
    const float denom = rsm[5];
    #pragma unroll
    for (int i = 0; i < 4; ++i) al[i * 256 + t] = ex[i] / denom;
    __syncthreads();

    // context partials: thread owns c-pairs d and d+256 (684 c = 342 dwords)
    float c0a = 0.f, c0b = 0.f, c1a = 0.f, c1b = 0.f;
    const int d0 = t, d1 = t + 256;
    const unsigned int* Xr =
        (const unsigned int*)(Xt + (size_t)(b * HWn + hhc * 64) * CPAD);
    for (int hl = 0; hl < 64; ++hl) {
        const float a = al[hhc * 64 + hl];
        const unsigned int* row = Xr + (size_t)hl * (CPAD / 2);
        unsigned int u0 = row[d0];
        c0a = fmaf(a, bf2f((unsigned short)(u0 & 0xffffu)), c0a);
        c0b = fmaf(a, bf2f((unsigned short)(u0 >> 16)),     c0b);
        if (d1 < 342) {
            unsigned int u1 = row[d1];
            c1a = fmaf(a, bf2f((unsigned short)(u1 & 0xffffu)), c1a);
            c1b = fmaf(a, bf2f((unsigned short)(u1 >> 16)),     c1b);
        }
    }
    atomicAdd(&out[b * Cn + 2 * d0],     c0a);
    atomicAdd(&out[b * Cn + 2 * d0 + 1], c0b);
    if (d1 < 342) {
        atomicAdd(&out[b * Cn + 2 * d1],     c1a);
        atomicAdd(&out[b * Cn + 2 * d1 + 1], c1b);
    }

    if (hhc == 0) {
        #pragma unroll
        for (int i = 0; i < 4; ++i) {
            int p = i * 256 + t;
            float a = al[p];
            out[OUT_ALPHA + b * HWn + p] = a;
            out[OUT_ASUM  + b * HWn + p] = a + asum[b * HWn + p];
        }
    }
}

// ---------------------------------------------------------------------------
extern "C" void kernel_launch(void* const* d_in, const int* in_sizes, int n_in,
                              void* d_out, int out_size, void* d_ws, size_t ws_size,
                              hipStream_t stream)
{
    const float* X      = (const float*)d_in[0];
    const float* hidden = (const float*)d_in[1];
    const float* asum   = (const float*)d_in[2];
    const float* mask   = (const float*)d_in[3];
    const float* Wh     = (const float*)d_in[4];
    const float* bh     = (const float*)d_in[5];
    const float* Wec    = (const float*)d_in[6];
    const float* bec    = (const float*)d_in[7];
    const float* Wac    = (const float*)d_in[8];
    const float* Waw    = (const float*)d_in[9];
    const float* Wv     = (const float*)d_in[10];
    (void)in_sizes; (void)n_in; (void)out_size; (void)ws_size;

    float* out = (float*)d_out;
    // ws layout (16B-aligned base): Xt | VTbf | query | energy
    unsigned short* Xt   = (unsigned short*)d_ws;            // 32*1024*832
    unsigned short* VTbf = Xt + (size_t)Bn * HWn * CPAD;     // 512*832
    float* query  = (float*)(VTbf + (size_t)An * CPAD);      // 16384
    float* energy = query + 16384;                           // 32768

    hipMemsetAsync(out, 0, OUT_ALPHA * sizeof(float), stream);  // context accum
    k_prep   <<<dim3(1056),   dim3(256), 0, stream>>>(X, asum, hidden, Wh, bh, bec,
                                                      Wec, Wac, Waw, query, VTbf, Xt);
    k_energy <<<dim3(16, 32), dim3(256), 0, stream>>>(Xt, Wv, query, VTbf, energy);
    k_ctx    <<<dim3(16, 32), dim3(256), 0, stream>>>(Xt, energy, mask, asum, out);
}

// Round 9
// 263.386 us; speedup vs baseline: 1.3006x; 1.3006x over previous
//
#include <hip/hip_runtime.h>
#include <math.h>

// Problem constants
#define Bn   32
#define Cn   684
#define Hn   16
#define Wn   64
#define HWn  1024
#define HIDn 256
#define An   512
#define KKn  121           // 11*11
#define CREAL 805          // 684 + 121
#define CPAD 832           // 26 chunks of 32 (VTbf row stride)
#define NSTEP 26

// Output layout (flat fp32): context [32,684] | alpha [32,1024] | alpha_sum_new [32,1024]
#define OUT_ALPHA 21888
#define OUT_ASUM  (21888 + 32768)

typedef short short8 __attribute__((ext_vector_type(8)));     // 8 bf16 = 4 VGPRs
typedef float floatx4 __attribute__((ext_vector_type(4)));    // MFMA acc

__device__ __forceinline__ unsigned short f2bf(float f) {
    union { float f; unsigned int i; } v; v.f = f;
    unsigned int i = v.i;
    return (unsigned short)((i + 0x7fffu + ((i >> 16) & 1u)) >> 16);
}
__device__ __forceinline__ unsigned int pack2bf(float v0, float v1) {
    unsigned int u0 = __float_as_uint(v0), u1 = __float_as_uint(v1);
    u0 = (u0 + 0x7fffu + ((u0 >> 16) & 1u)) >> 16;
    u1 = (u1 + 0x7fffu + ((u1 >> 16) & 1u)) & 0xffff0000u;
    return u0 | u1;
}

// ---------------------------------------------------------------------------
// K_prep: fused  (blocks 0..511: build VTbf row a)  (blocks 512..543: query b)
//   VTbf [512 a][832 k] bf16, k-contiguous:
//     k 0..683 = Wec[a][k]; 684..804 = sum_c Waw[a,c]*Wac[c,ij]; 805..831 = 0
__global__ __launch_bounds__(256) void k_prep(
    const float* __restrict__ hidden,
    const float* __restrict__ Wh,
    const float* __restrict__ bh,
    const float* __restrict__ bec,
    const float* __restrict__ Wec,
    const float* __restrict__ Wac,
    const float* __restrict__ Waw,
    float* __restrict__ query,
    unsigned short* __restrict__ VTbf)
{
    __shared__ float sbuf[512];
    __shared__ float wac_s[64 * KKn];   // 31 KB k-chunk of Wac
    const int blk = blockIdx.x, t = threadIdx.x;
    if (blk < 512) {
        const int a = blk;
        sbuf[t]       = Waw[(size_t)a * 512 + t];
        sbuf[t + 256] = Waw[(size_t)a * 512 + t + 256];
        for (int cp = t; cp < Cn; cp += 256)
            VTbf[(size_t)a * CPAD + cp] = f2bf(Wec[(size_t)a * Cn + cp]);
        float s = 0.f;
        for (int kb = 0; kb < 8; ++kb) {
            __syncthreads();
            for (int i = t; i < 64 * KKn; i += 256)
                wac_s[i] = Wac[kb * 64 * KKn + i];     // coalesced
            __syncthreads();
            if (t < KKn) {
                #pragma unroll 8
                for (int kk = 0; kk < 64; ++kk)
                    s = fmaf(sbuf[kb * 64 + kk], wac_s[kk * KKn + t], s);
            }
        }
        if (t < KKn)
            VTbf[(size_t)a * CPAD + Cn + t] = f2bf(s);
        for (int cp = CREAL + t; cp < CPAD; cp += 256)
            VTbf[(size_t)a * CPAD + cp] = 0;
    } else {
        const int b = blk - 512;
        sbuf[t] = (t < HIDn) ? hidden[b * HIDn + t] : 0.f;
        __syncthreads();
        for (int a = t; a < An; a += 256) {
            const float4* wp = (const float4*)(Wh + (size_t)a * HIDn);
            float s = bh[a] + bec[a];
            #pragma unroll 8
            for (int i = 0; i < HIDn / 4; ++i) {
                float4 w = wp[i];
                s = fmaf(sbuf[4 * i],     w.x, s);
                s = fmaf(sbuf[4 * i + 1], w.y, s);
                s = fmaf(sbuf[4 * i + 2], w.z, s);
                s = fmaf(sbuf[4 * i + 3], w.w, s);
            }
            query[b * An + a] = s;
        }
    }
}

// ---------------------------------------------------------------------------
// K_energy v8 (hybrid): B-fragments direct from L2-resident VTbf (register
// dbuf, no LDS/DMA); A staged via small LDS dbuf with 2-set register X
// prefetch. Barrier waits only on lgkmcnt. Block = (b,hh): M=64, N=512, K=832.
__device__ __forceinline__ float fetchU(const float* __restrict__ Xb,
                                        const float* plane,
                                        int m, int row) {
    if (row < Cn)   return Xb[(size_t)row * HWn + m];
    if (row < CREAL) {
        int ij = row - Cn; int di = ij / 11, dj = ij - di * 11;
        return plane[di * 74 + m + dj];
    }
    return 0.f;
}

__global__ __launch_bounds__(256, 2) void k_energy(
    const float* __restrict__ X,
    const float* __restrict__ asum,
    const float* __restrict__ Wv,
    const float* __restrict__ query,
    const unsigned short* __restrict__ VTbf,
    float* __restrict__ energy)
{
    __shared__ unsigned short As[2 * 64 * 40];   // A dbuf [m][k], stride 40
    __shared__ float red[64 * 65];
    __shared__ float plane[11 * 74 + 2];
    __shared__ float qs[An];
    __shared__ float wvs[An];

    const int t = threadIdx.x;
    const int hh = blockIdx.x, b = blockIdx.y;
    const int w = t >> 6, lane = t & 63;
    const int q = lane >> 4, r = lane & 15;
    const int mA = lane, koA = w;              // A-staging map

    const float* Xb = X + (size_t)b * Cn * HWn + hh * Wn;     // + row*HWn + m
    const unsigned short* Brow = VTbf + (size_t)(w * 128 + r) * CPAD + q * 8;

    // ---- prologue: plane / qs / wvs
    for (int i = t; i < 11 * 74; i += 256) {
        int di = i / 74, cc = i - di * 74;
        int h2 = hh + di - 5, w2 = cc - 5;
        float v = 0.f;
        if (h2 >= 0 && h2 < Hn && w2 >= 0 && w2 < Wn)
            v = asum[b * HWn + h2 * Wn + w2];
        plane[i] = v;
    }
    qs[t]        = query[b * An + t];
    qs[t + 256]  = query[b * An + t + 256];
    wvs[t]       = Wv[t];
    wvs[t + 256] = Wv[t + 256];

    // A chunk 0 -> As[0] (rows 0..31 pure X); xpA <- chunk 1; xpB <- chunk 2
    {
        const float* xp = Xb + (size_t)(koA * 8) * HWn + mA;
        unsigned int pk[4];
        #pragma unroll
        for (int jj = 0; jj < 4; ++jj)
            pk[jj] = pack2bf(xp[(size_t)(2 * jj) * HWn], xp[(size_t)(2 * jj + 1) * HWn]);
        *(uint4*)&As[mA * 40 + koA * 8] = make_uint4(pk[0], pk[1], pk[2], pk[3]);
    }
    float xpA[8], xpB[8];
    {
        const float* xp = Xb + (size_t)(32 + koA * 8) * HWn + mA;
        #pragma unroll
        for (int jj = 0; jj < 8; ++jj) xpA[jj] = xp[(size_t)jj * HWn];
    }
    {
        const float* xp = Xb + (size_t)(64 + koA * 8) * HWn + mA;
        #pragma unroll
        for (int jj = 0; jj < 8; ++jj) xpB[jj] = xp[(size_t)jj * HWn];
    }
    // B chunk 0 -> bfrA
    short8 bfrA[8], bfrB[8], af[4];
    #pragma unroll
    for (int nf = 0; nf < 8; ++nf)
        bfrA[nf] = *(const short8*)(Brow + (size_t)(nf * 16) * CPAD);
    __syncthreads();

    floatx4 acc[4][8];
    #pragma unroll
    for (int mf = 0; mf < 4; ++mf)
        #pragma unroll
        for (int nf = 0; nf < 8; ++nf)
            acc[mf][nf] = (floatx4){0.f, 0.f, 0.f, 0.f};

    for (int i = 0; i < 13; ++i) {
        const int ch0 = 2 * i, ch1 = 2 * i + 1;
        // ======== chunk ch0 : A in As[0], B in bfrA ========
        #pragma unroll
        for (int mf = 0; mf < 4; ++mf)
            af[mf] = *(const short8*)&As[(mf * 16 + r) * 40 + q * 8];
        #pragma unroll
        for (int nf = 0; nf < 8; ++nf)   // B for ch1
            bfrB[nf] = *(const short8*)(Brow + (size_t)(nf * 16) * CPAD + ch1 * 32);
        {   // ds_write A(ch1) from xpA (loaded one body ago)
            unsigned int pk[4];
            #pragma unroll
            for (int jj = 0; jj < 4; ++jj)
                pk[jj] = pack2bf(xpA[2 * jj], xpA[2 * jj + 1]);
            *(uint4*)&As[64 * 40 + mA * 40 + koA * 8] = make_uint4(pk[0], pk[1], pk[2], pk[3]);
        }
        if (2 * i + 3 < NSTEP) {   // xpA <- X(ch0+3)
            const int c3 = (2 * i + 3) * 32;
            if (c3 + 31 < Cn) {
                const float* xp = Xb + (size_t)(c3 + koA * 8) * HWn + mA;
                #pragma unroll
                for (int jj = 0; jj < 8; ++jj) xpA[jj] = xp[(size_t)jj * HWn];
            } else {
                #pragma unroll
                for (int jj = 0; jj < 8; ++jj)
                    xpA[jj] = fetchU(Xb, plane, mA, c3 + koA * 8 + jj);
            }
        }
        #pragma unroll
        for (int mf = 0; mf < 4; ++mf)
            #pragma unroll
            for (int nf = 0; nf < 8; ++nf)
                acc[mf][nf] = __builtin_amdgcn_mfma_f32_16x16x32_bf16(
                    af[mf], bfrA[nf], acc[mf][nf], 0, 0, 0);
        __syncthreads();
        // ======== chunk ch1 : A in As[1], B in bfrB ========
        #pragma unroll
        for (int mf = 0; mf < 4; ++mf)
            af[mf] = *(const short8*)&As[64 * 40 + (mf * 16 + r) * 40 + q * 8];
        if (ch1 + 1 < NSTEP) {
            #pragma unroll
            for (int nf = 0; nf < 8; ++nf)   // B for ch1+1
                bfrA[nf] = *(const short8*)(Brow + (size_t)(nf * 16) * CPAD + (ch1 + 1) * 32);
            {   // ds_write A(ch1+1) from xpB
                unsigned int pk[4];
                #pragma unroll
                for (int jj = 0; jj < 4; ++jj)
                    pk[jj] = pack2bf(xpB[2 * jj], xpB[2 * jj + 1]);
                *(uint4*)&As[mA * 40 + koA * 8] = make_uint4(pk[0], pk[1], pk[2], pk[3]);
            }
        }
        if (2 * i + 4 < NSTEP) {   // xpB <- X(ch1+3)
            const int c4 = (2 * i + 4) * 32;
            if (c4 + 31 < Cn) {
                const float* xp = Xb + (size_t)(c4 + koA * 8) * HWn + mA;
                #pragma unroll
                for (int jj = 0; jj < 8; ++jj) xpB[jj] = xp[(size_t)jj * HWn];
            } else {
                #pragma unroll
                for (int jj = 0; jj < 8; ++jj)
                    xpB[jj] = fetchU(Xb, plane, mA, c4 + koA * 8 + jj);
            }
        }
        #pragma unroll
        for (int mf = 0; mf < 4; ++mf)
            #pragma unroll
            for (int nf = 0; nf < 8; ++nf)
                acc[mf][nf] = __builtin_amdgcn_mfma_f32_16x16x32_bf16(
                    af[mf], bfrB[nf], acc[mf][nf], 0, 0, 0);
        __syncthreads();
    }

    // ---- epilogue: e[m] = sum_n Wv[n]*tanh(acc + query[n])
    float ep[16];
    #pragma unroll
    for (int i = 0; i < 16; ++i) ep[i] = 0.f;
    #pragma unroll
    for (int nf = 0; nf < 8; ++nf) {
        int n = w * 128 + nf * 16 + r;
        float qv = qs[n], wv = wvs[n];
        #pragma unroll
        for (int mf = 0; mf < 4; ++mf)
            #pragma unroll
            for (int rg = 0; rg < 4; ++rg) {
                float x = acc[mf][nf][rg] + qv;
                float e2 = __expf(2.f * x);
                float th = 1.f - 2.f * __builtin_amdgcn_rcpf(e2 + 1.f);
                ep[mf * 4 + rg] += wv * th;
            }
    }
    #pragma unroll
    for (int mf = 0; mf < 4; ++mf)
        #pragma unroll
        for (int rg = 0; rg < 4; ++rg)
            red[(mf * 16 + q * 4 + rg) * 65 + w * 16 + r] = ep[mf * 4 + rg];
    __syncthreads();
    if (t < 64) {
        float s = 0.f;
        #pragma unroll 16
        for (int i = 0; i < 64; ++i) s += red[t * 65 + i];
        energy[b * HWn + hh * Wn + t] = s;
    }
}

// ---------------------------------------------------------------------------
// K_ctx: fused softmax + context. Grid (171, 32). Each block recomputes the
// cheap 1024-wide softmax, then 4 context channels; block x==0 writes
// alpha / alpha_sum_new.
__global__ __launch_bounds__(256) void k_ctx(
    const float* __restrict__ X,
    const float* __restrict__ energy,
    const float* __restrict__ mask,
    const float* __restrict__ asum,
    float* __restrict__ out)
{
    __shared__ float al[1024];
    __shared__ float rsm[8];
    const int bx = blockIdx.x, b = blockIdx.y;
    const int t = threadIdx.x, lane = t & 63, wid = t >> 6;

    float e[4], ex[4];
    #pragma unroll
    for (int i = 0; i < 4; ++i) e[i] = energy[b * HWn + i * 256 + t];
    float m = fmaxf(fmaxf(e[0], e[1]), fmaxf(e[2], e[3]));
    for (int off = 32; off >= 1; off >>= 1) m = fmaxf(m, __shfl_down(m, off, 64));
    if (lane == 0) rsm[wid] = m;
    __syncthreads();
    if (t == 0) rsm[4] = fmaxf(fmaxf(rsm[0], rsm[1]), fmaxf(rsm[2], rsm[3]));
    __syncthreads();
    const float M = rsm[4];
    float s = 0.f;
    #pragma unroll
    for (int i = 0; i < 4; ++i) {
        ex[i] = expf(e[i] - M) * mask[b * HWn + i * 256 + t];
        s += ex[i];
    }
    for (int off = 32; off >= 1; off >>= 1) s += __shfl_down(s, off, 64);
    __syncthreads();
    if (lane == 0) rsm[wid] = s;
    __syncthreads();
    if (t == 0) rsm[5] = rsm[0] + rsm[1] + rsm[2] + rsm[3] + 1e-10f;
    __syncthreads();
    const float denom = rsm[5];
    #pragma unroll
    for (int i = 0; i < 4; ++i) al[i * 256 + t] = ex[i] / denom;
    __syncthreads();

    const int c = bx * 4 + wid;
    const float* xp = X + ((size_t)(b * Cn + c)) * HWn;
    float s2 = 0.f;
    #pragma unroll
    for (int i = 0; i < 4; ++i) {
        int off = i * 256 + lane * 4;
        float4 x = *(const float4*)(xp + off);
        float4 a = *(const float4*)(al + off);
        s2 = fmaf(a.x, x.x, s2);
        s2 = fmaf(a.y, x.y, s2);
        s2 = fmaf(a.z, x.z, s2);
        s2 = fmaf(a.w, x.w, s2);
    }
    for (int off = 32; off >= 1; off >>= 1) s2 += __shfl_down(s2, off, 64);
    if (lane == 0) out[b * Cn + c] = s2;

    if (bx == 0) {
        #pragma unroll
        for (int i = 0; i < 4; ++i) {
            int p = i * 256 + t;
            float a = al[p];
            out[OUT_ALPHA + b * HWn + p] = a;
            out[OUT_ASUM  + b * HWn + p] = a + asum[b * HWn + p];
        }
    }
}

// ---------------------------------------------------------------------------
extern "C" void kernel_launch(void* const* d_in, const int* in_sizes, int n_in,
                              void* d_out, int out_size, void* d_ws, size_t ws_size,
                              hipStream_t stream)
{
    const float* X      = (const float*)d_in[0];
    const float* hidden = (const float*)d_in[1];
    const float* asum   = (const float*)d_in[2];
    const float* mask   = (const float*)d_in[3];
    const float* Wh     = (const float*)d_in[4];
    const float* bh     = (const float*)d_in[5];
    const float* Wec    = (const float*)d_in[6];
    const float* bec    = (const float*)d_in[7];
    const float* Wac    = (const float*)d_in[8];
    const float* Waw    = (const float*)d_in[9];
    const float* Wv     = (const float*)d_in[10];
    (void)in_sizes; (void)n_in; (void)out_size; (void)ws_size;

    float* out = (float*)d_out;
    float* ws = (float*)d_ws;
    float* query  = ws;                                    // 16384 floats
    float* energy = ws + 16384;                            // 32768
    unsigned short* VTbf = (unsigned short*)(ws + 16384 + 32768); // 512*832

    k_prep   <<<dim3(544),     dim3(256), 0, stream>>>(hidden, Wh, bh, bec,
                                                       Wec, Wac, Waw, query, VTbf);
    k_energy <<<dim3(16, 32),  dim3(256), 0, stream>>>(X, asum, Wv, query, VTbf, energy);
    k_ctx    <<<dim3(171, 32), dim3(256), 0, stream>>>(X, energy, mask, asum, out);
}